// Round 1
// baseline (508.316 us; speedup 1.0000x reference)
//
#include <hip/hip_runtime.h>
#include <stdint.h>

#define THREADS 192
#define DIM 9
#define NK 81                // output cols
#define F 81                 // contraction dim (i*9+j), padded to 96
#define NCHUNK 6             // K-chunks of 16 along f
#define TILE 32              // rows per wave-tile (one 32x32x16 MFMA row block)
#define GRID 1280            // 5 blocks/CU x 256 CUs; 15 waves/CU resident

typedef __attribute__((ext_vector_type(8))) short short8;   // 8 bf16 bit-patterns
typedef __attribute__((ext_vector_type(16))) float f32x16;  // MFMA 32x32 accumulator

__device__ inline unsigned short f32_bf16(float x) {        // RNE fp32 -> bf16 bits
    unsigned u = __float_as_uint(x);
    u += 0x7FFFu + ((u >> 16) & 1u);
    return (unsigned short)(u >> 16);
}
__device__ inline float bf16_f32(unsigned short h) {
    return __uint_as_float(((unsigned)h) << 16);
}

// Barrier-free design: each WAVE independently processes (32-row tile) x (its
// 32-col slice). Inputs staged per-wave via global_load_lds (double-buffered,
// counted vmcnt), A-fragments computed in registers (no P-LDS round trip).
__global__ __launch_bounds__(THREADS, 4)
void tp_mfma(const float* __restrict__ in1, const float* __restrict__ in2,
             const float* __restrict__ cb, float* __restrict__ out,
             int nrows, int ntiles) {
    // Per-wave double-buffered staging: 576 floats = 2304 B per buffer.
    //   floats [0,288)   = in1 rows of the tile (32 rows x 9 f32)
    //   floats [288,576) = in2 rows
    __shared__ __attribute__((aligned(16))) float s_in[3][2][576];   // 13.8 KB/block

    const int tid  = threadIdx.x;
    const int lane = tid & 63;
    const int wave = tid >> 6;          // column slice: cols [32*wave, 32*wave+32)
    const int l31  = lane & 31;
    const int h    = lane >> 5;
    const int kcol = 32 * wave + l31;

    // ---- Stationary B (= W) fragments, hi+lo bf16 split, in registers ----
    // B[kf][n]: n = l31, kf = h*8 + j within chunk c; f = c*16 + kf; W[f][k] = cb[k*81 + f]
    short8 Bhi[NCHUNK], Blo[NCHUNK];
    for (int c = 0; c < NCHUNK; ++c) {
        union { short8 v; unsigned short u[8]; } bh, bl;
        for (int j = 0; j < 8; ++j) {
            int f = c * 16 + h * 8 + j;
            float v = 0.0f;
            if (f < F && kcol < NK) v = cb[kcol * F + f];
            unsigned short hb = f32_bf16(v);
            bh.u[j] = hb;
            bl.u[j] = f32_bf16(v - bf16_f32(hb));
        }
        Bhi[c] = bh.v; Blo[c] = bl.v;
    }

    const unsigned lim16 = (unsigned)nrows * 36u - 16u;  // OOB clamp (16B loads)
    const unsigned lim4  = (unsigned)nrows * 36u - 4u;   // OOB clamp (4B loads)
    const uintptr_t p1 = (uintptr_t)in1;
    const uintptr_t p2 = (uintptr_t)in2;

    // Stage tile t's 2304 B (in1 rows ++ in2 rows) into this wave's buffer.
    // 3 full-wave rounds: 16B, 16B, 4B per lane. LDS dest is wave-uniform
    // base + lane*width (linear), global src is per-lane (clamped in-bounds).
    auto stage = [&](int t, int buf) {
        const unsigned tb = (unsigned)t * 1152u;
        float* dst0 = &s_in[wave][buf][0];
        {   // round 0: staged bytes [0,1024) -> all in1
            unsigned o = tb + (unsigned)lane * 16u;
            if (o > lim16) o = lim16;
            __builtin_amdgcn_global_load_lds(
                (__attribute__((address_space(1))) void*)(p1 + o),
                (__attribute__((address_space(3))) void*)dst0, 16, 0, 0);
        }
        {   // round 1: staged bytes [1024,2048): lanes 0-7 in1 tail, 8-63 in2
            unsigned bb = 1024u + (unsigned)lane * 16u;
            unsigned o1 = tb + bb;          if (o1 > lim16) o1 = lim16;
            unsigned o2 = tb + bb - 1152u;  if (o2 > lim16) o2 = lim16; // underflow for bb<1152 -> clamped, unselected
            uintptr_t src = (bb < 1152u) ? (p1 + o1) : (p2 + o2);
            __builtin_amdgcn_global_load_lds(
                (__attribute__((address_space(1))) void*)src,
                (__attribute__((address_space(3))) void*)(dst0 + 256), 16, 0, 0);
        }
        {   // round 2: staged bytes [2048,2304) -> all in2
            unsigned o = tb + 896u + (unsigned)lane * 4u;
            if (o > lim4) o = lim4;
            __builtin_amdgcn_global_load_lds(
                (__attribute__((address_space(1))) void*)(p2 + o),
                (__attribute__((address_space(3))) void*)(dst0 + 512), 4, 0, 0);
        }
    };

    int cur = 0;
    const int t0 = blockIdx.x;
    if (t0 < ntiles) stage(t0, 0);

    for (int t = t0; t < ntiles; t += gridDim.x) {
        const int tn = t + gridDim.x;
        if (tn < ntiles) stage(tn, cur ^ 1);   // prefetch next tile
        // Wait for the CURRENT buffer's loads: "all but 3 newest done" always
        // covers them (the 3 newest are the just-issued prefetch, or stores on
        // the final iteration). Robust to any extra VMEM ops the compiler adds.
        asm volatile("s_waitcnt vmcnt(3)" ::: "memory");
        __builtin_amdgcn_sched_barrier(0);

        const float* sa = &s_in[wave][cur][0];
        float a[DIM], b[DIM];
#pragma unroll
        for (int i = 0; i < DIM; ++i) {
            a[i] = sa[l31 * 9 + i];
            b[i] = sa[288 + l31 * 9 + i];
        }

        // A-fragments in registers: lane (h,l31) needs P[row=l31][f=c*16+8h+j].
        // Compute both halves with STATIC indices, select by h (cndmask, no
        // divergence, no runtime array indexing).
        short8 A[NCHUNK];
#pragma unroll
        for (int c = 0; c < NCHUNK; ++c) {
            union { short8 v; unsigned short u[8]; } av;
#pragma unroll
            for (int j = 0; j < 8; ++j) {
                const int f0 = c * 16 + j;
                const int f1 = f0 + 8;
                float q0 = (f0 < F) ? a[f0 / 9] * b[f0 % 9] : 0.0f;
                float q1 = (f1 < F) ? a[f1 / 9] * b[f1 % 9] : 0.0f;
                av.u[j] = f32_bf16(h ? q1 : q0);
            }
            A[c] = av.v;
        }

        f32x16 acc = {0.f,0.f,0.f,0.f, 0.f,0.f,0.f,0.f, 0.f,0.f,0.f,0.f, 0.f,0.f,0.f,0.f};
#pragma unroll
        for (int c = 0; c < NCHUNK; ++c) {
            acc = __builtin_amdgcn_mfma_f32_32x32x16_bf16(A[c], Bhi[c], acc, 0, 0, 0);
            acc = __builtin_amdgcn_mfma_f32_32x32x16_bf16(A[c], Blo[c], acc, 0, 0, 0);
        }

        // C/D: col = lane&31, row = (r&3) + 8*(r>>2) + 4*h   [m74/m101]
        if (kcol < NK) {
            const long r0 = (long)t * TILE;
            float* po = out + r0 * NK + (h * 4) * NK + kcol;
            if (r0 + TILE <= (long)nrows) {        // full tile: unguarded stores
#pragma unroll
                for (int r = 0; r < 16; ++r) {
                    const int mrow = (r & 3) + 8 * (r >> 2);
                    po[mrow * NK] = acc[r];        // compile-time offsets
                }
            } else {                               // tail tile (not hit at B=1M)
#pragma unroll
                for (int r = 0; r < 16; ++r) {
                    const int mrow = (r & 3) + 8 * (r >> 2);
                    if (r0 + mrow + 4 * h < (long)nrows) po[mrow * NK] = acc[r];
                }
            }
        }
        cur ^= 1;
    }
}

extern "C" void kernel_launch(void* const* d_in, const int* in_sizes, int n_in,
                              void* d_out, int out_size, void* d_ws, size_t ws_size,
                              hipStream_t stream) {
    const float* in1 = (const float*)d_in[0];
    const float* in2 = (const float*)d_in[1];
    const float* cb  = (const float*)d_in[2];
    float* out = (float*)d_out;

    int nrows  = in_sizes[0] / DIM;                 // 1048576
    int ntiles = (nrows + TILE - 1) / TILE;         // 32768 (exact, no tail)
    int grid = (GRID < ntiles) ? GRID : ntiles;

    tp_mfma<<<grid, THREADS, 0, stream>>>(in1, in2, cb, out, nrows, ntiles);
}

// Round 2
// 412.452 us; speedup vs baseline: 1.2324x; 1.2324x over previous
//
#include <hip/hip_runtime.h>
#include <stdint.h>

#define THREADS 192
#define DIM 9
#define NK 81                // output cols
#define F 81                 // contraction dim (i*9+j), padded to 96
#define NCHUNK 6             // K-chunks of 16 along f
#define TILE 32              // rows per tile (one 32x32x16 MFMA row block)
#define GRID 1280            // 5 blocks/CU x 256 CUs

typedef __attribute__((ext_vector_type(8))) short short8;   // 8 bf16 bit-patterns
typedef __attribute__((ext_vector_type(16))) float f32x16;  // MFMA 32x32 accumulator
typedef __attribute__((ext_vector_type(4))) float f32x4;

__device__ inline unsigned short f32_bf16(float x) {        // RNE fp32 -> bf16 bits
    unsigned u = __float_as_uint(x);
    u += 0x7FFFu + ((u >> 16) & 1u);
    return (unsigned short)(u >> 16);
}
__device__ inline float bf16_f32(unsigned short h) {
    return __uint_as_float(((unsigned)h) << 16);
}

// Per-wave input staging (global_load_lds, double-buffered, counted vmcnt) +
// block-level C transpose through LDS so output is written as contiguous,
// 64B-aligned dwordx4 full-line stores (tile region = t*10368 B, 10368%64==0).
// Raw s_barrier (no vmcnt drain) keeps the load prefetch pipeline alive.
__global__ __launch_bounds__(THREADS, 4)
void tp_mfma(const float* __restrict__ in1, const float* __restrict__ in2,
             const float* __restrict__ cb, float* __restrict__ out,
             int nrows, int ntiles) {
    __shared__ __attribute__((aligned(16))) float s_in[3][2][576];  // 13.8 KB
    __shared__ __attribute__((aligned(16))) float s_c[TILE * NK];   // 10.1 KB

    const int tid  = threadIdx.x;
    const int lane = tid & 63;
    const int wave = tid >> 6;          // column slice: cols [32*wave, 32*wave+32)
    const int l31  = lane & 31;
    const int h    = lane >> 5;
    const int kcol = 32 * wave + l31;

    // ---- Stationary B (= W) fragments, hi+lo bf16 split, in registers ----
    short8 Bhi[NCHUNK], Blo[NCHUNK];
    for (int c = 0; c < NCHUNK; ++c) {
        union { short8 v; unsigned short u[8]; } bh, bl;
        for (int j = 0; j < 8; ++j) {
            int f = c * 16 + h * 8 + j;
            float v = 0.0f;
            if (f < F && kcol < NK) v = cb[kcol * F + f];
            unsigned short hb = f32_bf16(v);
            bh.u[j] = hb;
            bl.u[j] = f32_bf16(v - bf16_f32(hb));
        }
        Bhi[c] = bh.v; Blo[c] = bl.v;
    }

    const unsigned lim16 = (unsigned)nrows * 36u - 16u;  // OOB clamp (16B loads)
    const unsigned lim4  = (unsigned)nrows * 36u - 4u;   // OOB clamp (4B loads)
    const uintptr_t p1 = (uintptr_t)in1;
    const uintptr_t p2 = (uintptr_t)in2;

    // Stage tile t's 2304 B (32 rows of in1 ++ 32 rows of in2): 3 full-wave
    // global_load_lds rounds (16B,16B,4B). LDS dest linear, global src per-lane.
    auto stage = [&](int t, int buf) {
        const unsigned tb = (unsigned)t * 1152u;
        float* dst0 = &s_in[wave][buf][0];
        {   unsigned o = tb + (unsigned)lane * 16u;
            if (o > lim16) o = lim16;
            __builtin_amdgcn_global_load_lds(
                (__attribute__((address_space(1))) void*)(p1 + o),
                (__attribute__((address_space(3))) void*)dst0, 16, 0, 0);
        }
        {   unsigned bb = 1024u + (unsigned)lane * 16u;
            unsigned o1 = tb + bb;          if (o1 > lim16) o1 = lim16;
            unsigned o2 = tb + bb - 1152u;  if (o2 > lim16) o2 = lim16;
            uintptr_t src = (bb < 1152u) ? (p1 + o1) : (p2 + o2);
            __builtin_amdgcn_global_load_lds(
                (__attribute__((address_space(1))) void*)src,
                (__attribute__((address_space(3))) void*)(dst0 + 256), 16, 0, 0);
        }
        {   unsigned o = tb + 896u + (unsigned)lane * 4u;
            if (o > lim4) o = lim4;
            __builtin_amdgcn_global_load_lds(
                (__attribute__((address_space(1))) void*)(p2 + o),
                (__attribute__((address_space(3))) void*)(dst0 + 512), 4, 0, 0);
        }
    };

    int cur = 0;
    const int t0 = blockIdx.x;
    if (t0 < ntiles) stage(t0, 0);

    for (int t = t0; t < ntiles; t += gridDim.x) {
        const int tn = t + gridDim.x;
        const bool hasn = (tn < ntiles);
        if (hasn) stage(tn, cur ^ 1);   // prefetch next tile (3 loads)

        // Wait for loads(t). Ops newer than loads(t) in this wave's vmem queue:
        //   stores from previous iter: 4 (only if t > t0)
        //   prefetch loads just issued: 3 (only if hasn)
        if (t == t0) {
            if (hasn) asm volatile("s_waitcnt vmcnt(3)" ::: "memory");
            else      asm volatile("s_waitcnt vmcnt(0)" ::: "memory");
        } else {
            if (hasn) asm volatile("s_waitcnt vmcnt(7)" ::: "memory");
            else      asm volatile("s_waitcnt vmcnt(4)" ::: "memory");
        }
        __builtin_amdgcn_sched_barrier(0);

        const float* sa = &s_in[wave][cur][0];
        float a[DIM], b[DIM];
#pragma unroll
        for (int i = 0; i < DIM; ++i) {
            a[i] = sa[l31 * 9 + i];
            b[i] = sa[288 + l31 * 9 + i];
        }

        // A-fragments in registers: lane (h,l31) needs P[row=l31][f=c*16+8h+j].
        // Static indices for both halves, select by h (no runtime indexing).
        short8 A[NCHUNK];
#pragma unroll
        for (int c = 0; c < NCHUNK; ++c) {
            union { short8 v; unsigned short u[8]; } av;
#pragma unroll
            for (int j = 0; j < 8; ++j) {
                const int f0 = c * 16 + j;
                const int f1 = f0 + 8;
                float q0 = (f0 < F) ? a[f0 / 9] * b[f0 % 9] : 0.0f;
                float q1 = (f1 < F) ? a[f1 / 9] * b[f1 % 9] : 0.0f;
                av.u[j] = f32_bf16(h ? q1 : q0);
            }
            A[c] = av.v;
        }

        f32x16 acc = {0.f,0.f,0.f,0.f, 0.f,0.f,0.f,0.f, 0.f,0.f,0.f,0.f, 0.f,0.f,0.f,0.f};
#pragma unroll
        for (int c = 0; c < NCHUNK; ++c) {
            acc = __builtin_amdgcn_mfma_f32_32x32x16_bf16(A[c], Bhi[c], acc, 0, 0, 0);
            acc = __builtin_amdgcn_mfma_f32_32x32x16_bf16(A[c], Blo[c], acc, 0, 0, 0);
        }

        // ---- C transpose through LDS ----
        // C/D: col = lane&31, row = (r&3) + 8*(r>>2) + 4*h   [m74/m101]
        // Writes: 32 consecutive cols per half-wave -> 2-way aliasing (free).
        if (kcol < NK) {
#pragma unroll
            for (int r = 0; r < 16; ++r) {
                const int mrow = (r & 3) + 8 * (r >> 2) + 4 * h;
                s_c[mrow * NK + kcol] = acc[r];
            }
        }
        asm volatile("s_waitcnt lgkmcnt(0)\ns_barrier" ::: "memory");

        // ---- Contiguous, aligned output stores ----
        // Tile region: out + t*10368 B, size 10368 B = 648 x dwordx4, 64B-aligned.
        const long r0 = (long)t * TILE;
        if (r0 + TILE <= (long)nrows) {            // full tile (always, at B=1M)
            const f32x4* sc4 = (const f32x4*)s_c;
            f32x4* o4 = (f32x4*)(out + r0 * NK);
#pragma unroll
            for (int q = 0; q < 4; ++q) {          // exactly 4 stores per thread
                int idx = tid + q * THREADS;       // 0..767
                int idc = (idx >= 648) ? idx - 648 : idx;  // clamp-dup (same value)
                o4[idc] = sc4[idc];
            }
        } else {                                   // tail tile (last iter only)
            for (int e = tid; e < TILE * NK; e += THREADS) {
                long g = r0 * NK + e;
                if (g < (long)nrows * NK) out[g] = s_c[e];
            }
        }
        asm volatile("s_barrier" ::: "memory");    // s_c reuse fence
        cur ^= 1;
    }
}

extern "C" void kernel_launch(void* const* d_in, const int* in_sizes, int n_in,
                              void* d_out, int out_size, void* d_ws, size_t ws_size,
                              hipStream_t stream) {
    const float* in1 = (const float*)d_in[0];
    const float* in2 = (const float*)d_in[1];
    const float* cb  = (const float*)d_in[2];
    float* out = (float*)d_out;

    int nrows  = in_sizes[0] / DIM;                 // 1048576
    int ntiles = (nrows + TILE - 1) / TILE;         // 32768 (exact, no tail)
    int grid = (GRID < ntiles) ? GRID : ntiles;

    tp_mfma<<<grid, THREADS, 0, stream>>>(in1, in2, cb, out, nrows, ntiles);
}